// Round 1
// baseline (356.201 us; speedup 1.0000x reference)
//
#include <hip/hip_runtime.h>
#include <hip/hip_bf16.h>
#include <math.h>

typedef __hip_bfloat16 bf16;
typedef __attribute__((ext_vector_type(8))) short short8;
typedef __attribute__((ext_vector_type(4))) float floatx4;

#define GLDS16(g, l) __builtin_amdgcn_global_load_lds( \
    (const __attribute__((address_space(1))) void*)(g), \
    (__attribute__((address_space(3))) void*)(l), 16, 0, 0)

__device__ __forceinline__ bf16 f2bf(float v) { return __float2bfloat16(v); }

// ---------------- weight convert + transpose: w[K][N] f32 -> wT[N][K] bf16
__global__ __launch_bounds__(256) void kconvT(const float* __restrict__ w,
                                              bf16* __restrict__ wT,
                                              int K, int N) {
  __shared__ float tile[32][33];
  const int n0 = blockIdx.x * 32, k0 = blockIdx.y * 32;
  const int tc = threadIdx.x & 31, tr = threadIdx.x >> 5;  // tr 0..7
#pragma unroll
  for (int p = 0; p < 4; p++)
    tile[tr + p * 8][tc] = w[(size_t)(k0 + tr + p * 8) * N + n0 + tc];
  __syncthreads();
#pragma unroll
  for (int p = 0; p < 4; p++)
    wT[(size_t)(n0 + tr + p * 8) * K + k0 + tc] = f2bf(tile[tc][tr + p * 8]);
}

// ---------------- LayerNorm: f32 [rows][768] -> bf16
__global__ __launch_bounds__(256) void kln(const float* __restrict__ x,
                                           const float* __restrict__ gw,
                                           const float* __restrict__ bw,
                                           bf16* __restrict__ out) {
  const int row = blockIdx.x, tid = threadIdx.x;
  const float* xr = x + (size_t)row * 768;
  float v0 = xr[tid], v1 = xr[tid + 256], v2 = xr[tid + 512];
  float s = v0 + v1 + v2;
  float s2 = v0 * v0 + v1 * v1 + v2 * v2;
#pragma unroll
  for (int off = 1; off < 64; off <<= 1) {
    s += __shfl_xor(s, off);
    s2 += __shfl_xor(s2, off);
  }
  __shared__ float red[8];
  const int wid = tid >> 6, lane = tid & 63;
  if (lane == 0) { red[wid] = s; red[4 + wid] = s2; }
  __syncthreads();
  s = red[0] + red[1] + red[2] + red[3];
  s2 = red[4] + red[5] + red[6] + red[7];
  const float mu = s * (1.f / 768.f);
  const float rst = rsqrtf(fmaxf(s2 * (1.f / 768.f) - mu * mu, 0.f) + 1e-5f);
  bf16* orow = out + (size_t)row * 768;
  orow[tid] = f2bf((v0 - mu) * rst * gw[tid] + bw[tid]);
  orow[tid + 256] = f2bf((v1 - mu) * rst * gw[tid + 256] + bw[tid + 256]);
  orow[tid + 512] = f2bf((v2 - mu) * rst * gw[tid + 512] + bw[tid + 512]);
}

// ---------------- GEMM: C[M,N] = A[M,K] * BT[N,K]^T, bf16 inputs, f32 accum
// EPI 0: +bias -> bf16   EPI 1: +bias+resid -> f32   EPI 2: +bias, GELU -> bf16
template <int EPI>
__global__ __launch_bounds__(256, 2) void kgemm(
    const bf16* __restrict__ A, const bf16* __restrict__ BT,
    const float* __restrict__ bias, const float* __restrict__ resid,
    bf16* __restrict__ outb, float* __restrict__ outf, int M, int N, int K) {
  __shared__ bf16 As[128 * 32];
  __shared__ bf16 Bs[128 * 32];
  const int tid = threadIdx.x;
  const int wid = tid >> 6, lane = tid & 63, g = lane >> 4, q = lane & 15;
  const int wr = wid >> 1, wc = wid & 1;
  const int row0 = blockIdx.y * 128, col0 = blockIdx.x * 128;
  floatx4 acc[4][4] = {};
  const int r0 = tid >> 2;        // staging row (inst 0)
  const int c0 = (tid & 3) * 8;   // staging col
  const bf16* Ab = A + (size_t)row0 * K;
  const bf16* Bb = BT + (size_t)col0 * K;

  for (int k0 = 0; k0 < K; k0 += 32) {
    GLDS16(Ab + (size_t)r0 * K + k0 + c0, (char*)As + wid * 1024);
    GLDS16(Ab + (size_t)(r0 + 64) * K + k0 + c0, (char*)As + 4096 + wid * 1024);
    GLDS16(Bb + (size_t)r0 * K + k0 + c0, (char*)Bs + wid * 1024);
    GLDS16(Bb + (size_t)(r0 + 64) * K + k0 + c0, (char*)Bs + 4096 + wid * 1024);
    __syncthreads();
    short8 af[4], bfr[4];
#pragma unroll
    for (int m = 0; m < 4; m++)
      af[m] = *(const short8*)&As[(wr * 64 + m * 16 + q) * 32 + g * 8];
#pragma unroll
    for (int n = 0; n < 4; n++)
      bfr[n] = *(const short8*)&Bs[(wc * 64 + n * 16 + q) * 32 + g * 8];
#pragma unroll
    for (int m = 0; m < 4; m++)
#pragma unroll
      for (int n = 0; n < 4; n++)
        acc[m][n] =
            __builtin_amdgcn_mfma_f32_16x16x32_bf16(af[m], bfr[n], acc[m][n], 0, 0, 0);
    __syncthreads();
  }

#pragma unroll
  for (int n = 0; n < 4; n++) {
    const int col = col0 + wc * 64 + n * 16 + q;
    const float bv = bias[col];
#pragma unroll
    for (int m = 0; m < 4; m++) {
      const int rowb = row0 + wr * 64 + m * 16 + g * 4;
#pragma unroll
      for (int r = 0; r < 4; r++) {
        const size_t idx = (size_t)(rowb + r) * N + col;
        const float v = acc[m][n][r] + bv;
        if (EPI == 0) {
          outb[idx] = f2bf(v);
        } else if (EPI == 1) {
          outf[idx] = v + resid[idx];
        } else {
          const float t = tanhf(0.7978845608028654f * (v + 0.044715f * v * v * v));
          outb[idx] = f2bf(0.5f * v * (1.0f + t));
        }
      }
    }
  }
}

// ---------------- causal flash attention, bf16 in/out, f32 online softmax
// qkv: [B*T][2304] bf16 (q|k|v each 768, head h at h*64). y: [B*T][768] bf16.
__global__ __launch_bounds__(256, 2) void kattn(const bf16* __restrict__ qkv,
                                                bf16* __restrict__ y) {
  const int T = 2048, C3 = 2304;
  const int tid = threadIdx.x, wid = tid >> 6, lane = tid & 63;
  const int g = lane >> 4, qi = lane & 15;
  const int qblk = blockIdx.x, h = blockIdx.y, b = blockIdx.z;
  const int q0 = qblk * 64 + wid * 16;
  const bf16* Qb = qkv + (size_t)b * T * C3 + h * 64;
  const bf16* Kb = Qb + 768;
  const bf16* Vb = Qb + 1536;
  __shared__ short VT2[4][64][8];   // [kv/8][d][kv%8] — conflict-even transpose
  __shared__ bf16 P[4][16][40];     // per-wave P tile, stride 40 (16B-aligned rows)

  short8 qf[2];
#pragma unroll
  for (int s = 0; s < 2; s++)
    qf[s] = *(const short8*)(Qb + (size_t)(q0 + qi) * C3 + s * 32 + g * 8);

  float m_run[4], l_run[4];
  floatx4 o[4] = {};
#pragma unroll
  for (int r = 0; r < 4; r++) { m_run[r] = -1e30f; l_run[r] = 0.f; }

  const int kv_end = qblk * 64 + 64;
  const int vd = tid & 63, vk = tid >> 6;

  for (int kv0 = 0; kv0 < kv_end; kv0 += 32) {
    // stage V transposed: thread gathers 8 kv values for one d column
    {
      short8 tmp;
#pragma unroll
      for (int j = 0; j < 8; j++)
        tmp[j] = ((const short*)Vb)[(size_t)(kv0 + vk * 8 + j) * C3 + vd];
      *(short8*)&VT2[vk][vd][0] = tmp;
    }
    __syncthreads();

    // S = Q K^T  (16q x 32kv per wave)
    floatx4 sacc[2] = {};
#pragma unroll
    for (int c = 0; c < 2; c++)
#pragma unroll
      for (int s = 0; s < 2; s++) {
        short8 kf =
            *(const short8*)(Kb + (size_t)(kv0 + c * 16 + qi) * C3 + s * 32 + g * 8);
        sacc[c] = __builtin_amdgcn_mfma_f32_16x16x32_bf16(qf[s], kf, sacc[c], 0, 0, 0);
      }

    // online softmax (rows live at (g*4+r, col qi))
#pragma unroll
    for (int r = 0; r < 4; r++) {
      const int qrow = q0 + g * 4 + r;
      float s0 = sacc[0][r] * 0.125f;
      float s1 = sacc[1][r] * 0.125f;
      if (kv0 + qi > qrow) s0 = -1e30f;
      if (kv0 + 16 + qi > qrow) s1 = -1e30f;
      float mx = fmaxf(s0, s1);
#pragma unroll
      for (int off = 1; off < 16; off <<= 1) mx = fmaxf(mx, __shfl_xor(mx, off));
      const float mn = fmaxf(m_run[r], mx);
      const float al = __expf(m_run[r] - mn);
      const float p0 = __expf(s0 - mn), p1 = __expf(s1 - mn);
      float ps = p0 + p1;
#pragma unroll
      for (int off = 1; off < 16; off <<= 1) ps += __shfl_xor(ps, off);
      l_run[r] = l_run[r] * al + ps;
      m_run[r] = mn;
#pragma unroll
      for (int n = 0; n < 4; n++) o[n][r] *= al;
      P[wid][g * 4 + r][qi] = f2bf(p0);
      P[wid][g * 4 + r][16 + qi] = f2bf(p1);
    }
    __syncthreads();

    // O += P V
    short8 pf = *(const short8*)&P[wid][qi][g * 8];
#pragma unroll
    for (int n = 0; n < 4; n++) {
      short8 vf = *(const short8*)&VT2[g][n * 16 + qi][0];
      o[n] = __builtin_amdgcn_mfma_f32_16x16x32_bf16(pf, vf, o[n], 0, 0, 0);
    }
    __syncthreads();
  }

#pragma unroll
  for (int n = 0; n < 4; n++)
#pragma unroll
    for (int r = 0; r < 4; r++)
      y[(size_t)(b * T + q0 + g * 4 + r) * 768 + h * 64 + n * 16 + qi] =
          f2bf(o[n][r] / l_run[r]);
}

// ---------------- host side
extern "C" void kernel_launch(void* const* d_in, const int* in_sizes, int n_in,
                              void* d_out, int out_size, void* d_ws, size_t ws_size,
                              hipStream_t stream) {
  const float* x      = (const float*)d_in[0];
  const float* ln1_g  = (const float*)d_in[1];
  const float* ln1_b  = (const float*)d_in[2];
  const float* w_attn = (const float*)d_in[3];
  const float* b_attn = (const float*)d_in[4];
  const float* w_proj = (const float*)d_in[5];
  const float* b_proj = (const float*)d_in[6];
  const float* ln2_g  = (const float*)d_in[7];
  const float* ln2_b  = (const float*)d_in[8];
  const float* w_fc   = (const float*)d_in[9];
  const float* b_fc   = (const float*)d_in[10];
  const float* w_fc2  = (const float*)d_in[11];
  const float* b_fc2  = (const float*)d_in[12];
  float* out = (float*)d_out;

  const int M = 4096;  // B*T
  char* p = (char*)d_ws;
  bf16* wT_attn = (bf16*)p; p += (size_t)2304 * 768 * 2;   // 3.54 MB
  bf16* wT_proj = (bf16*)p; p += (size_t)768 * 768 * 2;    // 1.18 MB
  bf16* wT_fc   = (bf16*)p; p += (size_t)3072 * 768 * 2;   // 4.72 MB
  bf16* wT_fc2  = (bf16*)p; p += (size_t)768 * 3072 * 2;   // 4.72 MB
  bf16* h       = (bf16*)p; p += (size_t)M * 768 * 2;      // 6.29 MB (also h2)
  bf16* qkv     = (bf16*)p;                                 // 18.87 MB
  bf16* yb      = (bf16*)(p + (size_t)M * 2304 * 2);       // 6.29 MB
  bf16* act     = qkv;      p += (size_t)M * 2304 * 2 + (size_t)M * 768 * 2;
  float* x1     = (float*)p;                                // 12.58 MB

  // weights -> bf16 transposed
  kconvT<<<dim3(2304 / 32, 768 / 32), 256, 0, stream>>>(w_attn, wT_attn, 768, 2304);
  kconvT<<<dim3(768 / 32, 768 / 32), 256, 0, stream>>>(w_proj, wT_proj, 768, 768);
  kconvT<<<dim3(3072 / 32, 768 / 32), 256, 0, stream>>>(w_fc, wT_fc, 768, 3072);
  kconvT<<<dim3(768 / 32, 3072 / 32), 256, 0, stream>>>(w_fc2, wT_fc2, 3072, 768);

  // attention branch
  kln<<<M, 256, 0, stream>>>(x, ln1_g, ln1_b, h);
  kgemm<0><<<dim3(2304 / 128, M / 128), 256, 0, stream>>>(
      h, wT_attn, b_attn, nullptr, qkv, nullptr, M, 2304, 768);
  kattn<<<dim3(32, 12, 2), 256, 0, stream>>>(qkv, yb);
  kgemm<1><<<dim3(768 / 128, M / 128), 256, 0, stream>>>(
      yb, wT_proj, b_proj, x, nullptr, x1, M, 768, 768);

  // MLP branch
  kln<<<M, 256, 0, stream>>>(x1, ln2_g, ln2_b, h);
  kgemm<2><<<dim3(3072 / 128, M / 128), 256, 0, stream>>>(
      h, wT_fc, b_fc, nullptr, act, nullptr, M, 3072, 768);
  kgemm<1><<<dim3(768 / 128, M / 128), 256, 0, stream>>>(
      act, wT_fc2, b_fc2, x1, nullptr, out, M, 768, 3072);
}

// Round 2
// 311.987 us; speedup vs baseline: 1.1417x; 1.1417x over previous
//
#include <hip/hip_runtime.h>
#include <hip/hip_bf16.h>
#include <math.h>

typedef __hip_bfloat16 bf16;
typedef __attribute__((ext_vector_type(8))) short short8;
typedef __attribute__((ext_vector_type(4))) float floatx4;

#define GLDS16(g, l) __builtin_amdgcn_global_load_lds( \
    (const __attribute__((address_space(1))) void*)(g), \
    (__attribute__((address_space(3))) void*)(l), 16, 0, 0)

__device__ __forceinline__ bf16 f2bf(float v) { return __float2bfloat16(v); }

// ---------------- weight convert + transpose: w[K][N] f32 -> wT[N][K] bf16
__global__ __launch_bounds__(256) void kconvT(const float* __restrict__ w,
                                              bf16* __restrict__ wT,
                                              int K, int N) {
  __shared__ float tile[32][33];
  const int n0 = blockIdx.x * 32, k0 = blockIdx.y * 32;
  const int tc = threadIdx.x & 31, tr = threadIdx.x >> 5;  // tr 0..7
#pragma unroll
  for (int p = 0; p < 4; p++)
    tile[tr + p * 8][tc] = w[(size_t)(k0 + tr + p * 8) * N + n0 + tc];
  __syncthreads();
#pragma unroll
  for (int p = 0; p < 4; p++)
    wT[(size_t)(n0 + tr + p * 8) * K + k0 + tc] = f2bf(tile[tc][tr + p * 8]);
}

// ---------------- LayerNorm: f32 [rows][768] -> bf16
__global__ __launch_bounds__(256) void kln(const float* __restrict__ x,
                                           const float* __restrict__ gw,
                                           const float* __restrict__ bw,
                                           bf16* __restrict__ out) {
  const int row = blockIdx.x, tid = threadIdx.x;
  const float* xr = x + (size_t)row * 768;
  float v0 = xr[tid], v1 = xr[tid + 256], v2 = xr[tid + 512];
  float s = v0 + v1 + v2;
  float s2 = v0 * v0 + v1 * v1 + v2 * v2;
#pragma unroll
  for (int off = 1; off < 64; off <<= 1) {
    s += __shfl_xor(s, off);
    s2 += __shfl_xor(s2, off);
  }
  __shared__ float red[8];
  const int wid = tid >> 6, lane = tid & 63;
  if (lane == 0) { red[wid] = s; red[4 + wid] = s2; }
  __syncthreads();
  s = red[0] + red[1] + red[2] + red[3];
  s2 = red[4] + red[5] + red[6] + red[7];
  const float mu = s * (1.f / 768.f);
  const float rst = rsqrtf(fmaxf(s2 * (1.f / 768.f) - mu * mu, 0.f) + 1e-5f);
  bf16* orow = out + (size_t)row * 768;
  orow[tid] = f2bf((v0 - mu) * rst * gw[tid] + bw[tid]);
  orow[tid + 256] = f2bf((v1 - mu) * rst * gw[tid + 256] + bw[tid + 256]);
  orow[tid + 512] = f2bf((v2 - mu) * rst * gw[tid + 512] + bw[tid + 512]);
}

// ---------------- GEMM: C[M,N] = A[M,K] * BT[N,K]^T, bf16 inputs, f32 accum
// EPI 0: +bias -> bf16   EPI 1: +bias+resid -> f32   EPI 2: +bias, GELU -> bf16
// BN: 128 (waves 2x2, frags 4x4) or 64 (waves 4x1, frags 2x4)
template <int BN, int EPI>
__global__ __launch_bounds__(256, 2) void kgemm(
    const bf16* __restrict__ A, const bf16* __restrict__ BT,
    const float* __restrict__ bias, const float* __restrict__ resid,
    bf16* __restrict__ outb, float* __restrict__ outf, int M, int N, int K) {
  __shared__ bf16 As[128 * 32];
  __shared__ bf16 Bs[BN * 32];
  const int tid = threadIdx.x;
  const int wid = tid >> 6, lane = tid & 63, g = lane >> 4, q = lane & 15;
  constexpr int FM = (BN == 128) ? 4 : 2;
  constexpr int FN = 4;
  constexpr int WM = (BN == 128) ? 64 : 32;
  const int wr = (BN == 128) ? (wid >> 1) : wid;
  const int wc = (BN == 128) ? (wid & 1) : 0;
  const int row0 = blockIdx.y * 128, col0 = blockIdx.x * BN;
  floatx4 acc[FM][FN] = {};
  const int r0 = tid >> 2;        // staging row (inst 0)
  const int c0 = (tid & 3) * 8;   // staging col
  const bf16* Ab = A + (size_t)row0 * K;
  const bf16* Bb = BT + (size_t)col0 * K;

  for (int k0 = 0; k0 < K; k0 += 32) {
    GLDS16(Ab + (size_t)r0 * K + k0 + c0, (char*)As + wid * 1024);
    GLDS16(Ab + (size_t)(r0 + 64) * K + k0 + c0, (char*)As + 4096 + wid * 1024);
    GLDS16(Bb + (size_t)r0 * K + k0 + c0, (char*)Bs + wid * 1024);
    if constexpr (BN == 128)
      GLDS16(Bb + (size_t)(r0 + 64) * K + k0 + c0, (char*)Bs + 4096 + wid * 1024);
    __syncthreads();
    short8 af[FM], bfr[FN];
#pragma unroll
    for (int m = 0; m < FM; m++)
      af[m] = *(const short8*)&As[(wr * WM + m * 16 + q) * 32 + g * 8];
#pragma unroll
    for (int n = 0; n < FN; n++)
      bfr[n] = *(const short8*)&Bs[(wc * 64 + n * 16 + q) * 32 + g * 8];
#pragma unroll
    for (int m = 0; m < FM; m++)
#pragma unroll
      for (int n = 0; n < FN; n++)
        acc[m][n] =
            __builtin_amdgcn_mfma_f32_16x16x32_bf16(af[m], bfr[n], acc[m][n], 0, 0, 0);
    __syncthreads();
  }

#pragma unroll
  for (int n = 0; n < FN; n++) {
    const int col = col0 + wc * 64 + n * 16 + q;
    const float bv = bias[col];
#pragma unroll
    for (int m = 0; m < FM; m++) {
      const int rowb = row0 + wr * WM + m * 16 + g * 4;
#pragma unroll
      for (int r = 0; r < 4; r++) {
        const size_t idx = (size_t)(rowb + r) * N + col;
        const float v = acc[m][n][r] + bv;
        if (EPI == 0) {
          outb[idx] = f2bf(v);
        } else if (EPI == 1) {
          outf[idx] = v + resid[idx];
        } else {
          const float t = tanhf(0.7978845608028654f * (v + 0.044715f * v * v * v));
          outb[idx] = f2bf(0.5f * v * (1.0f + t));
        }
      }
    }
  }
}

// ---------------- causal flash attention v2
// 512 threads = 2 wave-groups; each group handles half the KV tiles (tiles of
// 64), partials merged in LDS at the end. Double-buffered transposed V tiles,
// one barrier per tile, prefetch of tile t+1 issued before computing tile t.
// qkv: [B*T][2304] bf16 (q|k|v each 768, head h at h*64). y: [B*T][768] bf16.
__global__ __launch_bounds__(512, 4) void kattn(const bf16* __restrict__ qkv,
                                                bf16* __restrict__ y) {
  const int T = 2048, C3 = 2304;
  const int tid = threadIdx.x;
  const int wid = tid >> 6, lane = tid & 63;
  const int g = lane >> 4, qi = lane & 15;
  const int w = wid & 3, gid = wid >> 2;
  const int qblk = gridDim.x - 1 - blockIdx.x;  // heavy blocks first
  const int h = blockIdx.y, b = blockIdx.z;
  const int q0w = qblk * 64 + w * 16;

  const bf16* Qb = qkv + (size_t)b * T * C3 + h * 64;
  const bf16* Kb = Qb + 768;
  const bf16* Vb = Qb + 1536;

  // VT: [group][buf][kv/8][d=64][kv%8] shorts = 32768 B
  // P:  [wave][16][72] bf16 = 18432 B    OM/ML alias VT for the final merge
  __shared__ __align__(16) char smem[51200];
  short* VT = (short*)smem;
  bf16* P = (bf16*)(smem + 32768);
  float* OM = (float*)smem;          // [64][66]
  float* ML = OM + 64 * 66;          // [128]: m then l

  const int nt = qblk + 1;           // KV tiles of 64
  const int nt0 = (nt + 1) >> 1;
  const int first = gid ? nt0 : 0;
  const int last = gid ? nt : nt0;
  const int iters = nt0;

  short8 qf[2];
#pragma unroll
  for (int s = 0; s < 2; s++)
    qf[s] = *(const short8*)(Qb + (size_t)(q0w + qi) * C3 + s * 32 + g * 8);

  float m_run[4], l_run[4];
  floatx4 o[4] = {};
#pragma unroll
  for (int r = 0; r < 4; r++) { m_run[r] = -1e30f; l_run[r] = 0.f; }

  const int sd = lane;  // d column this thread stages
  short8 st[2];

  // prologue: stage first tile
  if (first < last) {
    const int kv0 = first * 64;
#pragma unroll
    for (int jj = 0; jj < 2; jj++) {
      const int kvb = w * 2 + jj;
#pragma unroll
      for (int j = 0; j < 8; j++)
        st[jj][j] = ((const short*)Vb)[(size_t)(kv0 + kvb * 8 + j) * C3 + sd];
    }
#pragma unroll
    for (int jj = 0; jj < 2; jj++)
      *(short8*)&VT[(((gid * 2 + 0) * 8 + w * 2 + jj) * 64 + sd) * 8] = st[jj];
  }
  __syncthreads();

  for (int t = 0; t < iters; t++) {
    const int tg = first + t;
    const bool valid = tg < last;
    const bool nxt = tg + 1 < last;
    if (nxt) {  // issue prefetch loads early (latency hides under compute)
      const int kv0 = (tg + 1) * 64;
#pragma unroll
      for (int jj = 0; jj < 2; jj++) {
        const int kvb = w * 2 + jj;
#pragma unroll
        for (int j = 0; j < 8; j++)
          st[jj][j] = ((const short*)Vb)[(size_t)(kv0 + kvb * 8 + j) * C3 + sd];
      }
    }
    if (valid) {
      const int kv0 = tg * 64;
      // S = Q K^T : 16q x 64kv per wave
      floatx4 sacc[4] = {};
#pragma unroll
      for (int c = 0; c < 4; c++)
#pragma unroll
        for (int s = 0; s < 2; s++) {
          short8 kf =
              *(const short8*)(Kb + (size_t)(kv0 + c * 16 + qi) * C3 + s * 32 + g * 8);
          sacc[c] = __builtin_amdgcn_mfma_f32_16x16x32_bf16(qf[s], kf, sacc[c], 0, 0, 0);
        }
      const bool needm = (kv0 + 63 > q0w);
#pragma unroll
      for (int r = 0; r < 4; r++) {
        const int qrow = q0w + g * 4 + r;
        float sc[4];
#pragma unroll
        for (int c = 0; c < 4; c++) sc[c] = sacc[c][r] * 0.125f;
        if (needm) {
#pragma unroll
          for (int c = 0; c < 4; c++)
            if (kv0 + c * 16 + qi > qrow) sc[c] = -1e30f;
        }
        float mx = fmaxf(fmaxf(sc[0], sc[1]), fmaxf(sc[2], sc[3]));
#pragma unroll
        for (int off = 1; off < 16; off <<= 1) mx = fmaxf(mx, __shfl_xor(mx, off));
        const float mn = fmaxf(m_run[r], mx);
        const float al = __expf(m_run[r] - mn);
        float p[4], ps = 0.f;
#pragma unroll
        for (int c = 0; c < 4; c++) { p[c] = __expf(sc[c] - mn); ps += p[c]; }
#pragma unroll
        for (int off = 1; off < 16; off <<= 1) ps += __shfl_xor(ps, off);
        l_run[r] = l_run[r] * al + ps;
        m_run[r] = mn;
#pragma unroll
        for (int n = 0; n < 4; n++) o[n][r] *= al;
#pragma unroll
        for (int c = 0; c < 4; c++)
          P[(wid * 16 + g * 4 + r) * 72 + c * 16 + qi] = f2bf(p[c]);
      }
      // O += P V (P re-read as A-fragments; wave-local, no barrier needed)
#pragma unroll
      for (int ks = 0; ks < 2; ks++) {
        short8 pf = *(const short8*)&P[(wid * 16 + qi) * 72 + ks * 32 + g * 8];
#pragma unroll
        for (int n = 0; n < 4; n++) {
          short8 vf = *(const short8*)&VT[(((gid * 2 + (t & 1)) * 8 + ks * 4 + g) * 64 +
                                           n * 16 + qi) * 8];
          o[n] = __builtin_amdgcn_mfma_f32_16x16x32_bf16(pf, vf, o[n], 0, 0, 0);
        }
      }
    }
    if (nxt) {  // write prefetched tile into the other buffer
#pragma unroll
      for (int jj = 0; jj < 2; jj++)
        *(short8*)&VT[(((gid * 2 + ((t + 1) & 1)) * 8 + w * 2 + jj) * 64 + sd) * 8] =
            st[jj];
    }
    __syncthreads();
  }

  // merge group1 partials into group0, write y
  if (gid == 1) {
#pragma unroll
    for (int r = 0; r < 4; r++) {
      const int row = w * 16 + g * 4 + r;
      if (qi == 0) { ML[row] = m_run[r]; ML[64 + row] = l_run[r]; }
#pragma unroll
      for (int n = 0; n < 4; n++) OM[row * 66 + n * 16 + qi] = o[n][r];
    }
  }
  __syncthreads();
  if (gid == 0) {
#pragma unroll
    for (int r = 0; r < 4; r++) {
      const int row = w * 16 + g * 4 + r;
      const float m1 = ML[row], l1 = ML[64 + row];
      const float mn = fmaxf(m_run[r], m1);
      const float a0 = __expf(m_run[r] - mn);
      const float a1 = __expf(m1 - mn);
      const float inv = 1.0f / (l_run[r] * a0 + l1 * a1);
#pragma unroll
      for (int n = 0; n < 4; n++) {
        const float ov = (o[n][r] * a0 + OM[row * 66 + n * 16 + qi] * a1) * inv;
        y[(size_t)(b * T + qblk * 64 + row) * 768 + h * 64 + n * 16 + qi] = f2bf(ov);
      }
    }
  }
}

// ---------------- host side
extern "C" void kernel_launch(void* const* d_in, const int* in_sizes, int n_in,
                              void* d_out, int out_size, void* d_ws, size_t ws_size,
                              hipStream_t stream) {
  const float* x      = (const float*)d_in[0];
  const float* ln1_g  = (const float*)d_in[1];
  const float* ln1_b  = (const float*)d_in[2];
  const float* w_attn = (const float*)d_in[3];
  const float* b_attn = (const float*)d_in[4];
  const float* w_proj = (const float*)d_in[5];
  const float* b_proj = (const float*)d_in[6];
  const float* ln2_g  = (const float*)d_in[7];
  const float* ln2_b  = (const float*)d_in[8];
  const float* w_fc   = (const float*)d_in[9];
  const float* b_fc   = (const float*)d_in[10];
  const float* w_fc2  = (const float*)d_in[11];
  const float* b_fc2  = (const float*)d_in[12];
  float* out = (float*)d_out;

  const int M = 4096;  // B*T
  char* p = (char*)d_ws;
  bf16* wT_attn = (bf16*)p; p += (size_t)2304 * 768 * 2;
  bf16* wT_proj = (bf16*)p; p += (size_t)768 * 768 * 2;
  bf16* wT_fc   = (bf16*)p; p += (size_t)3072 * 768 * 2;
  bf16* wT_fc2  = (bf16*)p; p += (size_t)768 * 3072 * 2;
  bf16* h       = (bf16*)p; p += (size_t)M * 768 * 2;
  bf16* qkv     = (bf16*)p;
  bf16* yb      = (bf16*)(p + (size_t)M * 2304 * 2);
  bf16* act     = qkv;      p += (size_t)M * 2304 * 2 + (size_t)M * 768 * 2;
  float* x1     = (float*)p;

  // weights -> bf16 transposed
  kconvT<<<dim3(2304 / 32, 768 / 32), 256, 0, stream>>>(w_attn, wT_attn, 768, 2304);
  kconvT<<<dim3(768 / 32, 768 / 32), 256, 0, stream>>>(w_proj, wT_proj, 768, 768);
  kconvT<<<dim3(3072 / 32, 768 / 32), 256, 0, stream>>>(w_fc, wT_fc, 768, 3072);
  kconvT<<<dim3(768 / 32, 3072 / 32), 256, 0, stream>>>(w_fc2, wT_fc2, 3072, 768);

  // attention branch
  kln<<<M, 256, 0, stream>>>(x, ln1_g, ln1_b, h);
  kgemm<128, 0><<<dim3(2304 / 128, M / 128), 256, 0, stream>>>(
      h, wT_attn, b_attn, nullptr, qkv, nullptr, M, 2304, 768);
  kattn<<<dim3(32, 12, 2), 512, 0, stream>>>(qkv, yb);
  kgemm<64, 1><<<dim3(768 / 64, M / 128), 256, 0, stream>>>(
      yb, wT_proj, b_proj, x, nullptr, x1, M, 768, 768);

  // MLP branch
  kln<<<M, 256, 0, stream>>>(x1, ln2_g, ln2_b, h);
  kgemm<128, 2><<<dim3(3072 / 128, M / 128), 256, 0, stream>>>(
      h, wT_fc, b_fc, nullptr, act, nullptr, M, 3072, 768);
  kgemm<64, 1><<<dim3(768 / 64, M / 128), 256, 0, stream>>>(
      act, wT_fc2, b_fc2, x1, nullptr, out, M, 768, 3072);
}

// Round 3
// 304.983 us; speedup vs baseline: 1.1679x; 1.0230x over previous
//
#include <hip/hip_runtime.h>
#include <hip/hip_bf16.h>
#include <math.h>

typedef __hip_bfloat16 bf16;
typedef __attribute__((ext_vector_type(8))) short short8;
typedef __attribute__((ext_vector_type(4))) float floatx4;

#define GLDS16(g, l) __builtin_amdgcn_global_load_lds( \
    (const __attribute__((address_space(1))) void*)(g), \
    (__attribute__((address_space(3))) void*)(l), 16, 0, 0)

__device__ __forceinline__ bf16 f2bf(float v) { return __float2bfloat16(v); }

// ---------------- weight convert + transpose: w[K][N] f32 -> wT[N][K] bf16
__global__ __launch_bounds__(256) void kconvT(const float* __restrict__ w,
                                              bf16* __restrict__ wT,
                                              int K, int N) {
  __shared__ float tile[32][33];
  const int n0 = blockIdx.x * 32, k0 = blockIdx.y * 32;
  const int tc = threadIdx.x & 31, tr = threadIdx.x >> 5;  // tr 0..7
#pragma unroll
  for (int p = 0; p < 4; p++)
    tile[tr + p * 8][tc] = w[(size_t)(k0 + tr + p * 8) * N + n0 + tc];
  __syncthreads();
#pragma unroll
  for (int p = 0; p < 4; p++)
    wT[(size_t)(n0 + tr + p * 8) * K + k0 + tc] = f2bf(tile[tc][tr + p * 8]);
}

// ---------------- LayerNorm: f32 [rows][768] -> bf16
__global__ __launch_bounds__(256) void kln(const float* __restrict__ x,
                                           const float* __restrict__ gw,
                                           const float* __restrict__ bw,
                                           bf16* __restrict__ out) {
  const int row = blockIdx.x, tid = threadIdx.x;
  const float* xr = x + (size_t)row * 768;
  float v0 = xr[tid], v1 = xr[tid + 256], v2 = xr[tid + 512];
  float s = v0 + v1 + v2;
  float s2 = v0 * v0 + v1 * v1 + v2 * v2;
#pragma unroll
  for (int off = 1; off < 64; off <<= 1) {
    s += __shfl_xor(s, off);
    s2 += __shfl_xor(s2, off);
  }
  __shared__ float red[8];
  const int wid = tid >> 6, lane = tid & 63;
  if (lane == 0) { red[wid] = s; red[4 + wid] = s2; }
  __syncthreads();
  s = red[0] + red[1] + red[2] + red[3];
  s2 = red[4] + red[5] + red[6] + red[7];
  const float mu = s * (1.f / 768.f);
  const float rst = rsqrtf(fmaxf(s2 * (1.f / 768.f) - mu * mu, 0.f) + 1e-5f);
  bf16* orow = out + (size_t)row * 768;
  orow[tid] = f2bf((v0 - mu) * rst * gw[tid] + bw[tid]);
  orow[tid + 256] = f2bf((v1 - mu) * rst * gw[tid + 256] + bw[tid + 256]);
  orow[tid + 512] = f2bf((v2 - mu) * rst * gw[tid + 512] + bw[tid + 512]);
}

// ---------------- V transpose: qkv[b*T+t][1536 + h*64 + d] -> VT[b][h][d][t]
__global__ __launch_bounds__(256) void kxpose(const bf16* __restrict__ qkv,
                                              bf16* __restrict__ VT) {
  const int T = 2048, C3 = 2304;
  const int t0 = blockIdx.x * 64, h = blockIdx.y, b = blockIdx.z;
  const int tid = threadIdx.x;
  __shared__ short tile[64][66];
  const bf16* src = qkv + (size_t)b * T * C3 + 1536 + h * 64;
  // load: thread reads 16B (8 d) of rows t0+tr and t0+tr+32
  const int tr = tid >> 3, c = tid & 7;
#pragma unroll
  for (int p = 0; p < 2; p++) {
    short8 v = *(const short8*)(src + (size_t)(t0 + tr + p * 32) * C3 + c * 8);
    *(short8*)&tile[tr + p * 32][c * 8] = v;  // 66-stride broken by c*8 — ok, row base aligned
  }
  __syncthreads();
  // write: thread gathers 8 t for one d, stores 16B contiguous in t
  bf16* dst = VT + ((size_t)(b * 12 + h) * 64) * T + t0;
#pragma unroll
  for (int p = 0; p < 2; p++) {
    const int d = (tid >> 3) + p * 32, tc = tid & 7;
    short8 v;
#pragma unroll
    for (int j = 0; j < 8; j++) v[j] = tile[tc * 8 + j][d];
    *(short8*)(dst + (size_t)d * T + tc * 8) = v;
  }
}

// ---------------- GEMM: C[M,N] = A[M,K] * BT[N,K]^T, bf16 inputs, f32 accum
// EPI 0: +bias -> bf16   EPI 1: +bias+resid -> f32   EPI 2: +bias, GELU -> bf16
template <int BN, int EPI>
__global__ __launch_bounds__(256, 2) void kgemm(
    const bf16* __restrict__ A, const bf16* __restrict__ BT,
    const float* __restrict__ bias, const float* __restrict__ resid,
    bf16* __restrict__ outb, float* __restrict__ outf, int M, int N, int K) {
  __shared__ bf16 As[128 * 32];
  __shared__ bf16 Bs[BN * 32];
  const int tid = threadIdx.x;
  const int wid = tid >> 6, lane = tid & 63, g = lane >> 4, q = lane & 15;
  constexpr int FM = (BN == 128) ? 4 : 2;
  constexpr int FN = 4;
  constexpr int WM = (BN == 128) ? 64 : 32;
  const int wr = (BN == 128) ? (wid >> 1) : wid;
  const int wc = (BN == 128) ? (wid & 1) : 0;
  const int row0 = blockIdx.y * 128, col0 = blockIdx.x * BN;
  floatx4 acc[FM][FN] = {};
  const int r0 = tid >> 2;        // staging row (inst 0)
  const int c0 = (tid & 3) * 8;   // staging col
  const bf16* Ab = A + (size_t)row0 * K;
  const bf16* Bb = BT + (size_t)col0 * K;

  for (int k0 = 0; k0 < K; k0 += 32) {
    GLDS16(Ab + (size_t)r0 * K + k0 + c0, (char*)As + wid * 1024);
    GLDS16(Ab + (size_t)(r0 + 64) * K + k0 + c0, (char*)As + 4096 + wid * 1024);
    GLDS16(Bb + (size_t)r0 * K + k0 + c0, (char*)Bs + wid * 1024);
    if constexpr (BN == 128)
      GLDS16(Bb + (size_t)(r0 + 64) * K + k0 + c0, (char*)Bs + 4096 + wid * 1024);
    __syncthreads();
    short8 af[FM], bfr[FN];
#pragma unroll
    for (int m = 0; m < FM; m++)
      af[m] = *(const short8*)&As[(wr * WM + m * 16 + q) * 32 + g * 8];
#pragma unroll
    for (int n = 0; n < FN; n++)
      bfr[n] = *(const short8*)&Bs[(wc * 64 + n * 16 + q) * 32 + g * 8];
#pragma unroll
    for (int m = 0; m < FM; m++)
#pragma unroll
      for (int n = 0; n < FN; n++)
        acc[m][n] =
            __builtin_amdgcn_mfma_f32_16x16x32_bf16(af[m], bfr[n], acc[m][n], 0, 0, 0);
    __syncthreads();
  }

#pragma unroll
  for (int n = 0; n < FN; n++) {
    const int col = col0 + wc * 64 + n * 16 + q;
    const float bv = bias[col];
#pragma unroll
    for (int m = 0; m < FM; m++) {
      const int rowb = row0 + wr * WM + m * 16 + g * 4;
#pragma unroll
      for (int r = 0; r < 4; r++) {
        const size_t idx = (size_t)(rowb + r) * N + col;
        const float v = acc[m][n][r] + bv;
        if (EPI == 0) {
          outb[idx] = f2bf(v);
        } else if (EPI == 1) {
          outf[idx] = v + resid[idx];
        } else {
          const float t = tanhf(0.7978845608028654f * (v + 0.044715f * v * v * v));
          outb[idx] = f2bf(0.5f * v * (1.0f + t));
        }
      }
    }
  }
}

// ---------------- causal flash attention v3: barrier-free inner loop
// K read direct from qkv (L2), V read direct from VT[b][h][d][t] (L2).
// 512 threads = 2 wave-groups splitting the KV range; merge at the end.
__global__ __launch_bounds__(512, 4) void kattn(const bf16* __restrict__ qkv,
                                                const bf16* __restrict__ VT,
                                                bf16* __restrict__ y) {
  const int T = 2048, C3 = 2304;
  const int tid = threadIdx.x;
  const int wid = tid >> 6, lane = tid & 63;
  const int g = lane >> 4, qi = lane & 15;
  const int w = wid & 3, gid = wid >> 2;

  // XCD-chunked swizzle: 768 blocks = 8 XCDs x 96; logical id groups (b,h)
  const int bid = blockIdx.x;
  const int lb = (bid & 7) * 96 + (bid >> 3);
  const int qblk = 31 - (lb & 31);         // heavy blocks first within slab
  const int h = (lb >> 5) % 12, b = (lb >> 5) / 12;
  const int q0w = qblk * 64 + w * 16;

  const bf16* Qb = qkv + (size_t)b * T * C3 + h * 64;
  const bf16* Kb = Qb + 768;
  const bf16* VTb = VT + (size_t)(b * 12 + h) * 64 * T;

  // P: per-wave tile (wave-local, no barrier). Merge arrays alias P.
  __shared__ __align__(16) char smem[18432];
  bf16* P = (bf16*)smem;                 // [8][16][72]
  float* OM = (float*)smem;              // [64][66]
  float* ML = OM + 64 * 66;              // [128]

  const int nt = qblk + 1;               // KV tiles of 64
  const int nt0 = (nt + 1) >> 1;
  const int first = gid ? nt0 : 0;
  const int last = gid ? nt : nt0;

  short8 qf[2];
#pragma unroll
  for (int s = 0; s < 2; s++)
    qf[s] = *(const short8*)(Qb + (size_t)(q0w + qi) * C3 + s * 32 + g * 8);

  float m_run[4], l_run[4];
  floatx4 o[4] = {};
#pragma unroll
  for (int r = 0; r < 4; r++) { m_run[r] = -1e30f; l_run[r] = 0.f; }

  for (int tg = first; tg < last; tg++) {
    const int kv0 = tg * 64;
    // S = Q K^T : 16q x 64kv per wave, K fragments straight from global/L2
    floatx4 sacc[4] = {};
#pragma unroll
    for (int c = 0; c < 4; c++)
#pragma unroll
      for (int s = 0; s < 2; s++) {
        short8 kf =
            *(const short8*)(Kb + (size_t)(kv0 + c * 16 + qi) * C3 + s * 32 + g * 8);
        sacc[c] = __builtin_amdgcn_mfma_f32_16x16x32_bf16(qf[s], kf, sacc[c], 0, 0, 0);
      }
    const bool needm = (kv0 + 63 > q0w);
#pragma unroll
    for (int r = 0; r < 4; r++) {
      const int qrow = q0w + g * 4 + r;
      float sc[4];
#pragma unroll
      for (int c = 0; c < 4; c++) sc[c] = sacc[c][r] * 0.125f;
      if (needm) {
#pragma unroll
        for (int c = 0; c < 4; c++)
          if (kv0 + c * 16 + qi > qrow) sc[c] = -1e30f;
      }
      float mx = fmaxf(fmaxf(sc[0], sc[1]), fmaxf(sc[2], sc[3]));
#pragma unroll
      for (int off = 1; off < 16; off <<= 1) mx = fmaxf(mx, __shfl_xor(mx, off));
      const float mn = fmaxf(m_run[r], mx);
      const float al = __expf(m_run[r] - mn);
      float p[4], ps = 0.f;
#pragma unroll
      for (int c = 0; c < 4; c++) { p[c] = __expf(sc[c] - mn); ps += p[c]; }
#pragma unroll
      for (int off = 1; off < 16; off <<= 1) ps += __shfl_xor(ps, off);
      l_run[r] = l_run[r] * al + ps;
      m_run[r] = mn;
#pragma unroll
      for (int n = 0; n < 4; n++) o[n][r] *= al;
#pragma unroll
      for (int c = 0; c < 4; c++)
        P[(wid * 16 + g * 4 + r) * 72 + c * 16 + qi] = f2bf(p[c]);
    }
    // O += P V : P from wave-local LDS, V fragments straight from VT (L2)
#pragma unroll
    for (int ks = 0; ks < 2; ks++) {
      short8 pf = *(const short8*)&P[(wid * 16 + qi) * 72 + ks * 32 + g * 8];
#pragma unroll
      for (int n = 0; n < 4; n++) {
        short8 vf = *(const short8*)(VTb + (size_t)(n * 16 + qi) * T + kv0 + ks * 32 + g * 8);
        o[n] = __builtin_amdgcn_mfma_f32_16x16x32_bf16(pf, vf, o[n], 0, 0, 0);
      }
    }
  }

  // merge group1 partials into group0, write y
  __syncthreads();
  if (gid == 1) {
#pragma unroll
    for (int r = 0; r < 4; r++) {
      const int row = w * 16 + g * 4 + r;
      if (qi == 0) { ML[row] = m_run[r]; ML[64 + row] = l_run[r]; }
#pragma unroll
      for (int n = 0; n < 4; n++) OM[row * 66 + n * 16 + qi] = o[n][r];
    }
  }
  __syncthreads();
  if (gid == 0) {
#pragma unroll
    for (int r = 0; r < 4; r++) {
      const int row = w * 16 + g * 4 + r;
      const float m1 = ML[row], l1 = ML[64 + row];
      const float mn = fmaxf(m_run[r], m1);
      const float a0 = __expf(m_run[r] - mn);
      const float a1 = __expf(m1 - mn);
      const float inv = 1.0f / (l_run[r] * a0 + l1 * a1);
#pragma unroll
      for (int n = 0; n < 4; n++) {
        const float ov = (o[n][r] * a0 + OM[row * 66 + n * 16 + qi] * a1) * inv;
        y[(size_t)(b * T + qblk * 64 + row) * 768 + h * 64 + n * 16 + qi] = f2bf(ov);
      }
    }
  }
}

// ---------------- host side
extern "C" void kernel_launch(void* const* d_in, const int* in_sizes, int n_in,
                              void* d_out, int out_size, void* d_ws, size_t ws_size,
                              hipStream_t stream) {
  const float* x      = (const float*)d_in[0];
  const float* ln1_g  = (const float*)d_in[1];
  const float* ln1_b  = (const float*)d_in[2];
  const float* w_attn = (const float*)d_in[3];
  const float* b_attn = (const float*)d_in[4];
  const float* w_proj = (const float*)d_in[5];
  const float* b_proj = (const float*)d_in[6];
  const float* ln2_g  = (const float*)d_in[7];
  const float* ln2_b  = (const float*)d_in[8];
  const float* w_fc   = (const float*)d_in[9];
  const float* b_fc   = (const float*)d_in[10];
  const float* w_fc2  = (const float*)d_in[11];
  const float* b_fc2  = (const float*)d_in[12];
  float* out = (float*)d_out;

  const int M = 4096;  // B*T
  char* p = (char*)d_ws;
  bf16* wT_attn = (bf16*)p; p += (size_t)2304 * 768 * 2;
  bf16* wT_proj = (bf16*)p; p += (size_t)768 * 768 * 2;
  bf16* wT_fc   = (bf16*)p; p += (size_t)3072 * 768 * 2;
  bf16* wT_fc2  = (bf16*)p; p += (size_t)768 * 3072 * 2;
  bf16* h       = (bf16*)p; p += (size_t)M * 768 * 2;
  bf16* qkv     = (bf16*)p;
  bf16* yb      = (bf16*)(p + (size_t)M * 2304 * 2);
  bf16* act     = qkv;      p += (size_t)M * 2304 * 2 + (size_t)M * 768 * 2;
  float* x1     = (float*)p;
  bf16* VT      = (bf16*)p;  // aliases x1: VT dead before x1 is written

  // weights -> bf16 transposed
  kconvT<<<dim3(2304 / 32, 768 / 32), 256, 0, stream>>>(w_attn, wT_attn, 768, 2304);
  kconvT<<<dim3(768 / 32, 768 / 32), 256, 0, stream>>>(w_proj, wT_proj, 768, 768);
  kconvT<<<dim3(3072 / 32, 768 / 32), 256, 0, stream>>>(w_fc, wT_fc, 768, 3072);
  kconvT<<<dim3(768 / 32, 3072 / 32), 256, 0, stream>>>(w_fc2, wT_fc2, 3072, 768);

  // attention branch
  kln<<<M, 256, 0, stream>>>(x, ln1_g, ln1_b, h);
  kgemm<128, 0><<<dim3(2304 / 128, M / 128), 256, 0, stream>>>(
      h, wT_attn, b_attn, nullptr, qkv, nullptr, M, 2304, 768);
  kxpose<<<dim3(32, 12, 2), 256, 0, stream>>>(qkv, VT);
  kattn<<<dim3(768), 512, 0, stream>>>(qkv, VT, yb);
  kgemm<64, 1><<<dim3(768 / 64, M / 128), 256, 0, stream>>>(
      yb, wT_proj, b_proj, x, nullptr, x1, M, 768, 768);

  // MLP branch
  kln<<<M, 256, 0, stream>>>(x1, ln2_g, ln2_b, h);
  kgemm<128, 2><<<dim3(3072 / 128, M / 128), 256, 0, stream>>>(
      h, wT_fc, b_fc, nullptr, act, nullptr, M, 3072, 768);
  kgemm<64, 1><<<dim3(768 / 64, M / 128), 256, 0, stream>>>(
      act, wT_fc2, b_fc2, x1, nullptr, out, M, 768, 3072);
}